// Round 4
// baseline (504.557 us; speedup 1.0000x reference)
//
#include <hip/hip_runtime.h>
#include <stdint.h>

typedef __attribute__((ext_vector_type(8))) short bf16x8;   // 8 bf16 raw bits (4 VGPRs)
typedef __attribute__((ext_vector_type(4))) float f32x4;    // MFMA accumulator / vec load

static __device__ __forceinline__ uint16_t f2bf(float f) {
    uint32_t u;
    __builtin_memcpy(&u, &f, 4);
    return (uint16_t)((u + 0x7FFFu + ((u >> 16) & 1u)) >> 16);   // RNE
}

// ---------------------------------------------------------------------------
// K1: X = (I - A)^-1 B via forward substitution (fp32).
// Launch shape identical to the harness-verified round-0 kernel: 1 block x
// 128 threads, one 64 KB static LDS buffer. Thread d owns column d.
// Fix vs the 243us version: x[128] lived in per-thread registers and relied
// on full unroll of the 128-step loop; LLVM bailed -> runtime-indexed ->
// scratch -> serial ~900-cyc spill round-trips (VALUBusy 0.017%). Here x
// lives in LDS, one row per lane, quad-XOR-swizzled:
//     word = d*128 + (t ^ ((d&7)<<2))
// so a per-lane ds_read_b128 over consecutive t maps the 8 lane-groups onto
// 8 disjoint bank-quads (bank-quad = (q&7)^(d&7)) -> minimum-cycle b128.
// A-row reads are lane-invariant (uniform scalar/broadcast loads, A is 64 KB
// and L1/L2-resident); B reads coalesced. No lane reads another lane's x ->
// NO barriers anywhere in the kernel.
// ---------------------------------------------------------------------------
__global__ __launch_bounds__(128) void k1_solve(const float* __restrict__ Ag,
                                                const float* __restrict__ Bg,
                                                float* __restrict__ X) {
    __shared__ float xT[128 * 128];   // 64 KB: per-lane x row, quad-swizzled

    const int d  = threadIdx.x;       // 0..127 global column (owned by this lane)
    const int sw = (d & 7) << 2;      // quad swizzle (word units)
    float* xrow = &xT[d * 128];

    for (int s = 0; s < 128; ++s) {
        const float* Ar = Ag + s * 128;   // lane-uniform address
        float a0 = 0.f, a1 = 0.f, a2 = 0.f, a3 = 0.f;
        const int nq = s >> 2;
        for (int q = 0; q < nq; ++q) {
            f32x4 av = *reinterpret_cast<const f32x4*>(Ar + q * 4);
            f32x4 xv = *reinterpret_cast<const f32x4*>(xrow + ((q * 4) ^ sw));
            a0 += av[0] * xv[0];
            a1 += av[1] * xv[1];
            a2 += av[2] * xv[2];
            a3 += av[3] * xv[3];
        }
        float acc = (a0 + a1) + (a2 + a3);
        for (int t = nq * 4; t < s; ++t) acc += Ar[t] * xrow[t ^ sw];
        float xs = (Bg[s * 128 + d] + acc) / (1.0f - Ar[s]);
        xrow[s ^ sw] = xs;                // own-lane LDS write (RAW via lgkmcnt)
        X[s * 128 + d] = xs;              // coalesced fire-and-forget
    }
}

// ---------------------------------------------------------------------------
// K2: M[o][d] = sum_s C[o][s] * X[s][d] + D[o][d] (fp32 math), rounded to bf16
// directly in MFMA 16x16x32 fragment order (A-frag and B-frag share the same
// lane<->(index,k) mapping, so this buffer serves as the A-operand in k3):
//   lane = ((d>>3)&3)*16 + (o&15); j = d&7; frag f = (o>>4)*4 + (d>>5)
//   element index = (f*64 + lane)*8 + j
// ---------------------------------------------------------------------------
__global__ __launch_bounds__(128) void k2_makeM(const float* __restrict__ X,
                                                const float* __restrict__ Cg,
                                                const float* __restrict__ Dg,
                                                uint16_t* __restrict__ Mfrag) {
    const int o = blockIdx.x;    // 0..127 output row of M
    const int d = threadIdx.x;   // 0..127 column (k dim of the big GEMM)
    float a0 = 0.f, a1 = 0.f, a2 = 0.f, a3 = 0.f;
#pragma unroll
    for (int s = 0; s < 128; s += 4) {
        a0 += Cg[o * 128 + s + 0] * X[(s + 0) * 128 + d];
        a1 += Cg[o * 128 + s + 1] * X[(s + 1) * 128 + d];
        a2 += Cg[o * 128 + s + 2] * X[(s + 2) * 128 + d];
        a3 += Cg[o * 128 + s + 3] * X[(s + 3) * 128 + d];
    }
    float m = ((a0 + a1) + (a2 + a3)) + Dg[o * 128 + d];

    const int c = o >> 4, n = o & 15;
    const int t = d >> 5, r = d & 31;
    const int half = r >> 3, j = r & 7;
    const int lane = half * 16 + n;
    const int f = c * 4 + t;
    Mfrag[(f * 64 + lane) * 8 + j] = f2bf(m);
}

// ---------------------------------------------------------------------------
// K3: y = u @ M^T. 262144 rows, K=128, N=128. One 16-row tile per WAVE,
// grid 4096 x 256 thr. M staged once per block in LDS (32 KB).
// SWAPPED MFMA operands — acc = mfma(M, u): D[m=o][n=urow].
// C/D mapping (col=lane&15=urow, row=(lane>>4)*4+r=o) then puts each lane's
// 4 acc regs at 4 CONSECUTIVE output columns -> 8 global_store_dwordx4/lane
// instead of 32 scalar dword stores. u-frag (B-operand: n=lane&15=urow,
// k=(lane>>4)*8+j) uses the exact same per-lane load as before the swap.
// ---------------------------------------------------------------------------
__global__ __launch_bounds__(256, 4) void k3_gemm(const float* __restrict__ U,
                                                  const uint16_t* __restrict__ Mfrag,
                                                  float* __restrict__ Y) {
    __shared__ uint16_t Msh[16384];   // 32 KB: 32 frags x 64 lanes x 8 bf16
    {
        const uint4* src = reinterpret_cast<const uint4*>(Mfrag);
        uint4* dst = reinterpret_cast<uint4*>(Msh);
#pragma unroll
        for (int i = 0; i < 8; ++i)
            dst[threadIdx.x + 256 * i] = src[threadIdx.x + 256 * i];
    }
    __syncthreads();

    const int lane = threadIdx.x & 63;
    const int wid  = threadIdx.x >> 6;
    const int urow = lane & 15;   // u row within tile (B-operand n index)
    const int kh   = lane >> 4;   // k-octet (0..3), 8 contiguous k each

    const int rowbase = blockIdx.x * 64 + wid * 16;

    // Load + pack this wave's 16x128 u tile: 8 dwordx4 per lane.
    const float* up = U + (size_t)(rowbase + urow) * 128 + kh * 8;
    bf16x8 Afr[4];
#pragma unroll
    for (int t = 0; t < 4; ++t) {
        f32x4 lo = *reinterpret_cast<const f32x4*>(up + t * 32);
        f32x4 hi = *reinterpret_cast<const f32x4*>(up + t * 32 + 4);
        bf16x8 a;
#pragma unroll
        for (int j = 0; j < 4; ++j) {
            a[j]     = (short)f2bf(lo[j]);
            a[4 + j] = (short)f2bf(hi[j]);
        }
        Afr[t] = a;
    }

    f32x4 acc[8] = {};
#pragma unroll
    for (int c = 0; c < 8; ++c) {
#pragma unroll
        for (int t = 0; t < 4; ++t) {
            bf16x8 b = *reinterpret_cast<const bf16x8*>(Msh + ((c * 4 + t) * 64 + lane) * 8);
            acc[c] = __builtin_amdgcn_mfma_f32_16x16x32_bf16(b, Afr[t], acc[c], 0, 0, 0);
        }
    }

    // Lane writes row (rowbase+urow), cols c*16 + kh*4 + (0..3): f32x4 stores.
    float* yp = Y + (size_t)(rowbase + urow) * 128 + kh * 4;
#pragma unroll
    for (int c = 0; c < 8; ++c)
        *reinterpret_cast<f32x4*>(yp + c * 16) = acc[c];
}

// ---------------------------------------------------------------------------
extern "C" void kernel_launch(void* const* d_in, const int* in_sizes, int n_in,
                              void* d_out, int out_size, void* d_ws, size_t ws_size,
                              hipStream_t stream) {
    const float* u = (const float*)d_in[0];   // [32, 8192, 128] fp32
    const float* A = (const float*)d_in[1];   // [128, 128] fp32, lower-tri
    const float* B = (const float*)d_in[2];   // [128, 128] fp32
    const float* C = (const float*)d_in[3];   // [128, 128] fp32
    const float* D = (const float*)d_in[4];   // [128, 128] fp32

    float*    X     = (float*)d_ws;                          // 64 KB fp32
    uint16_t* Mfrag = (uint16_t*)((char*)d_ws + 65536);      // 32 KB bf16 frag order
    float*    Y     = (float*)d_out;                         // [32*8192, 128] fp32

    hipLaunchKernelGGL(k1_solve, dim3(1),    dim3(128), 0, stream, A, B, X);
    hipLaunchKernelGGL(k2_makeM, dim3(128),  dim3(128), 0, stream, X, C, D, Mfrag);
    hipLaunchKernelGGL(k3_gemm,  dim3(4096), dim3(256), 0, stream, u, Mfrag, Y);
}

// Round 5
// 317.902 us; speedup vs baseline: 1.5871x; 1.5871x over previous
//
#include <hip/hip_runtime.h>
#include <stdint.h>

typedef __attribute__((ext_vector_type(8))) short bf16x8;   // 8 bf16 raw bits (4 VGPRs)
typedef __attribute__((ext_vector_type(4))) float f32x4;    // MFMA accumulator / vec load

static __device__ __forceinline__ uint16_t f2bf(float f) {
    uint32_t u;
    __builtin_memcpy(&u, &f, 4);
    return (uint16_t)((u + 0x7FFFu + ((u >> 16) & 1u)) >> 16);   // RNE
}

// ---------------------------------------------------------------------------
// K1: X = (I - A)^-1 B via forward substitution (fp32).
// Round-4 evidence: x-in-LDS + A-in-GLOBAL = 266us (serial per-iteration
// global-load waits in the inner loop, VALUBusy 0.026%). Round-0 evidence:
// A-in-LDS + x-in-scratch = 243us. Both operands must be on-chip:
//   - 2 blocks x 64 threads. Columns independent -> block b owns d in
//     [64b, 64b+64), zero cross-lane traffic.
//   - x in LDS (32 KB), one row per lane, quad-XOR-swizzled:
//       word = dl*128 + (t ^ ((dl&7)<<2))
//     so per-lane ds_read_b128 over t puts the 8 lane-groups on 8 disjoint
//     bank-quads (minimum 8-sweep for 1KB/wave -> no excess conflicts).
//   - A streamed through LDS in 16-row panels (8 KB); B panel-staged (4 KB).
//     44 KB static total. Barriers only at panel boundaries (uniform).
// Critical path/step ~150-250cy (ds write->read + fma tree + rcp) -> ~13us.
// ---------------------------------------------------------------------------
__global__ __launch_bounds__(64) void k1_solve(const float* __restrict__ Ag,
                                               const float* __restrict__ Bg,
                                               float* __restrict__ X) {
    __shared__ float Ap[16 * 128];   // 8 KB: current 16-row A panel
    __shared__ float Bp[16 * 64];    // 4 KB: current 16-row B panel (this block's cols)
    __shared__ float xT[64 * 128];   // 32 KB: x transposed per-lane, quad-swizzled

    const int dl = threadIdx.x;               // 0..63 local column
    const int d  = blockIdx.x * 64 + dl;      // global column
    const int sw = (dl & 7) << 2;             // quad swizzle (word units)
    float* xrow = &xT[dl * 128];

    for (int p = 0; p < 8; ++p) {
        __syncthreads();   // previous panel's reads complete before overwrite
        {
            // Stage A rows [16p, 16p+16): 2048 words = 512 f32x4, 8 per lane.
            const f32x4* src = reinterpret_cast<const f32x4*>(Ag + p * 2048);
            f32x4* dst = reinterpret_cast<f32x4*>(Ap);
#pragma unroll
            for (int i = 0; i < 8; ++i) dst[i * 64 + dl] = src[i * 64 + dl];
#pragma unroll
            for (int i = 0; i < 16; ++i) Bp[i * 64 + dl] = Bg[(p * 16 + i) * 128 + d];
        }
        __syncthreads();

        for (int sl = 0; sl < 16; ++sl) {
            const int s = p * 16 + sl;
            const float* Ar = Ap + sl * 128;   // lane-uniform LDS address: broadcast
            float a0 = 0.f, a1 = 0.f, a2 = 0.f, a3 = 0.f;
            const int nq = s >> 2;
            for (int q = 0; q < nq; ++q) {
                f32x4 av = *reinterpret_cast<const f32x4*>(Ar + q * 4);
                f32x4 xv = *reinterpret_cast<const f32x4*>(xrow + ((q * 4) ^ sw));
                a0 += av[0] * xv[0];
                a1 += av[1] * xv[1];
                a2 += av[2] * xv[2];
                a3 += av[3] * xv[3];
            }
            float acc = (a0 + a1) + (a2 + a3);
            for (int t = nq * 4; t < s; ++t) acc += Ar[t] * xrow[t ^ sw];
            float xs = (Bp[sl * 64 + dl] + acc) / (1.0f - Ar[s]);
            xrow[s ^ sw] = xs;                 // own-lane LDS write (RAW via lgkmcnt)
            X[s * 128 + d] = xs;               // coalesced fire-and-forget
        }
    }
}

// ---------------------------------------------------------------------------
// K2: M[o][d] = sum_s C[o][s] * X[s][d] + D[o][d] (fp32 math), rounded to bf16
// directly in MFMA 16x16x32 fragment order (A-frag and B-frag share the same
// lane<->(index,k) mapping, so this buffer serves as the A-operand in k3):
//   lane = ((d>>3)&3)*16 + (o&15); j = d&7; frag f = (o>>4)*4 + (d>>5)
//   element index = (f*64 + lane)*8 + j
// ---------------------------------------------------------------------------
__global__ __launch_bounds__(128) void k2_makeM(const float* __restrict__ X,
                                                const float* __restrict__ Cg,
                                                const float* __restrict__ Dg,
                                                uint16_t* __restrict__ Mfrag) {
    const int o = blockIdx.x;    // 0..127 output row of M
    const int d = threadIdx.x;   // 0..127 column (k dim of the big GEMM)
    float a0 = 0.f, a1 = 0.f, a2 = 0.f, a3 = 0.f;
#pragma unroll
    for (int s = 0; s < 128; s += 4) {
        a0 += Cg[o * 128 + s + 0] * X[(s + 0) * 128 + d];
        a1 += Cg[o * 128 + s + 1] * X[(s + 1) * 128 + d];
        a2 += Cg[o * 128 + s + 2] * X[(s + 2) * 128 + d];
        a3 += Cg[o * 128 + s + 3] * X[(s + 3) * 128 + d];
    }
    float m = ((a0 + a1) + (a2 + a3)) + Dg[o * 128 + d];

    const int c = o >> 4, n = o & 15;
    const int t = d >> 5, r = d & 31;
    const int half = r >> 3, j = r & 7;
    const int lane = half * 16 + n;
    const int f = c * 4 + t;
    Mfrag[(f * 64 + lane) * 8 + j] = f2bf(m);
}

// ---------------------------------------------------------------------------
// K3: y = u @ M^T. 262144 rows, K=128, N=128. One 16-row tile per WAVE,
// grid 4096 x 256 thr. M staged once per block in LDS (32 KB).
// SWAPPED MFMA operands — acc = mfma(M, u): D[m=o][n=urow].
// C/D mapping (col=lane&15=urow, row=(lane>>4)*4+r=o) puts each lane's 4 acc
// regs at 4 CONSECUTIVE output columns -> 8 global_store_dwordx4/lane.
// u-frag (B-operand: n=lane&15=urow, k=(lane>>4)*8+j) per-lane load unchanged.
// Harness-verified this round: passed, absmax 0.00390625.
// ---------------------------------------------------------------------------
__global__ __launch_bounds__(256, 4) void k3_gemm(const float* __restrict__ U,
                                                  const uint16_t* __restrict__ Mfrag,
                                                  float* __restrict__ Y) {
    __shared__ uint16_t Msh[16384];   // 32 KB: 32 frags x 64 lanes x 8 bf16
    {
        const uint4* src = reinterpret_cast<const uint4*>(Mfrag);
        uint4* dst = reinterpret_cast<uint4*>(Msh);
#pragma unroll
        for (int i = 0; i < 8; ++i)
            dst[threadIdx.x + 256 * i] = src[threadIdx.x + 256 * i];
    }
    __syncthreads();

    const int lane = threadIdx.x & 63;
    const int wid  = threadIdx.x >> 6;
    const int urow = lane & 15;   // u row within tile (B-operand n index)
    const int kh   = lane >> 4;   // k-octet (0..3), 8 contiguous k each

    const int rowbase = blockIdx.x * 64 + wid * 16;

    // Load + pack this wave's 16x128 u tile: 8 dwordx4 per lane.
    const float* up = U + (size_t)(rowbase + urow) * 128 + kh * 8;
    bf16x8 Afr[4];
#pragma unroll
    for (int t = 0; t < 4; ++t) {
        f32x4 lo = *reinterpret_cast<const f32x4*>(up + t * 32);
        f32x4 hi = *reinterpret_cast<const f32x4*>(up + t * 32 + 4);
        bf16x8 a;
#pragma unroll
        for (int j = 0; j < 4; ++j) {
            a[j]     = (short)f2bf(lo[j]);
            a[4 + j] = (short)f2bf(hi[j]);
        }
        Afr[t] = a;
    }

    f32x4 acc[8] = {};
#pragma unroll
    for (int c = 0; c < 8; ++c) {
#pragma unroll
        for (int t = 0; t < 4; ++t) {
            bf16x8 b = *reinterpret_cast<const bf16x8*>(Msh + ((c * 4 + t) * 64 + lane) * 8);
            acc[c] = __builtin_amdgcn_mfma_f32_16x16x32_bf16(b, Afr[t], acc[c], 0, 0, 0);
        }
    }

    // Lane writes row (rowbase+urow), cols c*16 + kh*4 + (0..3): f32x4 stores.
    float* yp = Y + (size_t)(rowbase + urow) * 128 + kh * 4;
#pragma unroll
    for (int c = 0; c < 8; ++c)
        *reinterpret_cast<f32x4*>(yp + c * 16) = acc[c];
}

// ---------------------------------------------------------------------------
extern "C" void kernel_launch(void* const* d_in, const int* in_sizes, int n_in,
                              void* d_out, int out_size, void* d_ws, size_t ws_size,
                              hipStream_t stream) {
    const float* u = (const float*)d_in[0];   // [32, 8192, 128] fp32
    const float* A = (const float*)d_in[1];   // [128, 128] fp32, lower-tri
    const float* B = (const float*)d_in[2];   // [128, 128] fp32
    const float* C = (const float*)d_in[3];   // [128, 128] fp32
    const float* D = (const float*)d_in[4];   // [128, 128] fp32

    float*    X     = (float*)d_ws;                          // 64 KB fp32
    uint16_t* Mfrag = (uint16_t*)((char*)d_ws + 65536);      // 32 KB bf16 frag order
    float*    Y     = (float*)d_out;                         // [32*8192, 128] fp32

    hipLaunchKernelGGL(k1_solve, dim3(2),    dim3(64),  0, stream, A, B, X);
    hipLaunchKernelGGL(k2_makeM, dim3(128),  dim3(128), 0, stream, X, C, D, Mfrag);
    hipLaunchKernelGGL(k3_gemm,  dim3(4096), dim3(256), 0, stream, u, Mfrag, Y);
}